// Round 1
// baseline (6126.656 us; speedup 1.0000x reference)
//
#include <hip/hip_runtime.h>

#define Bz 32
#define Tz 64
#define Sz 400
#define Dz 512
#define G3 1536
#define VOC 32000
#define NEGC 1e12f

typedef __attribute__((ext_vector_type(8))) short short8;
typedef __attribute__((ext_vector_type(4))) float f32x4;

__device__ __forceinline__ float sigm(float x){ return 1.f/(1.f+__expf(-x)); }
__device__ __forceinline__ float tanhfast(float x){ float e=__expf(2.f*x); return 1.f - 2.f/(e+1.f); }
__device__ __forceinline__ unsigned short f2bf(float f){
  unsigned int u = __float_as_uint(f);
  u = (u + 0x7FFFu + ((u>>16)&1u)) >> 16;
  return (unsigned short)u;
}

// ---------------- repack emb (b,t,e)->(t*B+b,e), also fill rin cols 0..511 ----
__global__ __launch_bounds__(128) void repack_emb(const float* __restrict__ emb,
    float* __restrict__ embT, float* __restrict__ rin){
  int tb = blockIdx.x; int t = tb >> 5, b = tb & 31;
  int e4 = threadIdx.x; // 128 threads * 4 floats
  float4 v = *(const float4*)&emb[((size_t)b*Tz + t)*Dz + e4*4];
  *(float4*)&embT[(size_t)tb*Dz + e4*4] = v;
  *(float4*)&rin[(size_t)tb*G3 + e4*4] = v;
}

// ---------------- generic transpose: out[e*ldo+j] = in[j*ldi+off+e] ----------
__global__ __launch_bounds__(256) void transpose_k(const float* __restrict__ in, int ldi, int off,
    float* __restrict__ out, int ldo){
  __shared__ float tile[32][33];
  int j0 = blockIdx.x*32, e0 = blockIdx.y*32;
  int tx = threadIdx.x & 31, ty = threadIdx.x >> 5; // 8 rows per pass
  for (int jj = ty; jj < 32; jj += 8)
    tile[jj][tx] = in[(size_t)(j0+jj)*ldi + off + e0 + tx];
  __syncthreads();
  for (int ee = ty; ee < 32; ee += 8)
    out[(size_t)(e0+ee)*ldo + j0 + tx] = tile[tx][ee];
}

__global__ __launch_bounds__(256) void zero_f32(float* __restrict__ p, int n){
  int i = blockIdx.x*256 + threadIdx.x;
  if (i < n) p[i] = 0.f;
}

__global__ __launch_bounds__(256) void cast_bf(const float* __restrict__ in,
    unsigned short* __restrict__ out, int n){
  for (int i = blockIdx.x*256 + threadIdx.x; i < n; i += gridDim.x*256)
    out[i] = f2bf(in[i]);
}

// ---------------- f32 tiled GEMM: C[M,N] = A[M,K] @ B[N,K]^T + bias ----------
__global__ __launch_bounds__(256) void gemm_f32(const float* __restrict__ A, int lda,
    const float* __restrict__ Bm, int ldb, const float* __restrict__ bias,
    float* __restrict__ C, int ldc, int M, int N, int K){
  __shared__ __align__(16) float As[16][68];
  __shared__ __align__(16) float Bs[16][68];
  int tid = threadIdx.x;
  int m0 = blockIdx.x * 64, n0 = blockIdx.y * 64;
  int tx = tid & 15, ty = tid >> 4;
  float acc[4][4] = {};
  int lr = tid >> 2;
  int lk = (tid & 3) << 2;
  for (int k0 = 0; k0 < K; k0 += 16){
    int m = m0 + lr;
    float4 va = (m < M) ? *(const float4*)&A[(size_t)m*lda + k0 + lk] : make_float4(0,0,0,0);
    int n = n0 + lr;
    float4 vb = (n < N) ? *(const float4*)&Bm[(size_t)n*ldb + k0 + lk] : make_float4(0,0,0,0);
    As[lk+0][lr]=va.x; As[lk+1][lr]=va.y; As[lk+2][lr]=va.z; As[lk+3][lr]=va.w;
    Bs[lk+0][lr]=vb.x; Bs[lk+1][lr]=vb.y; Bs[lk+2][lr]=vb.z; Bs[lk+3][lr]=vb.w;
    __syncthreads();
    #pragma unroll
    for (int kk = 0; kk < 16; kk++){
      float4 a = *(const float4*)&As[kk][ty*4];
      float4 b = *(const float4*)&Bs[kk][tx*4];
      float av[4] = {a.x,a.y,a.z,a.w};
      float bv[4] = {b.x,b.y,b.z,b.w};
      #pragma unroll
      for (int i = 0; i < 4; i++)
        #pragma unroll
        for (int j = 0; j < 4; j++)
          acc[i][j] += av[i]*bv[j];
    }
    __syncthreads();
  }
  #pragma unroll
  for (int i = 0; i < 4; i++){
    int m = m0 + ty*4 + i;
    if (m >= M) continue;
    #pragma unroll
    for (int j = 0; j < 4; j++){
      int n = n0 + tx*4 + j;
      if (n < N) C[(size_t)m*ldc + n] = acc[i][j] + bias[n];
    }
  }
}

// ---------------- bf16 MFMA GEMM: out = A_bf @ B_bf^T + bias ----------------
// mode 0: out[m*N+n] = v ; mode 1: logits layout remap + (==0 -> -NEG)
__global__ __launch_bounds__(256) void mfma_bf16(const unsigned short* __restrict__ A, int lda,
    const unsigned short* __restrict__ Bm, int ldb, const float* __restrict__ bias,
    float* __restrict__ out, int N, int K, int mode, int Vext){
  __shared__ __align__(16) unsigned short As[128][40];
  __shared__ __align__(16) unsigned short Bs[128][40];
  int tid = threadIdx.x;
  int m0 = blockIdx.x * 128, n0 = blockIdx.y * 128;
  int wid = tid >> 6, lane = tid & 63;
  int wm = (wid >> 1) * 64, wn = (wid & 1) * 64;
  f32x4 acc[4][4];
  #pragma unroll
  for (int r = 0; r < 4; r++)
    #pragma unroll
    for (int c = 0; c < 4; c++) acc[r][c] = (f32x4){0.f,0.f,0.f,0.f};
  int lr = tid >> 1;
  int lk = (tid & 1) * 16;
  int frow = lane & 15, kg = (lane >> 4) * 8;
  for (int k0 = 0; k0 < K; k0 += 32){
    *(uint4*)&As[lr][lk]     = *(const uint4*)&A[(size_t)(m0+lr)*lda + k0 + lk];
    *(uint4*)&As[lr][lk+8]   = *(const uint4*)&A[(size_t)(m0+lr)*lda + k0 + lk + 8];
    *(uint4*)&Bs[lr][lk]     = *(const uint4*)&Bm[(size_t)(n0+lr)*ldb + k0 + lk];
    *(uint4*)&Bs[lr][lk+8]   = *(const uint4*)&Bm[(size_t)(n0+lr)*ldb + k0 + lk + 8];
    __syncthreads();
    short8 af[4], bf[4];
    #pragma unroll
    for (int r = 0; r < 4; r++) af[r] = *(const short8*)&As[wm + r*16 + frow][kg];
    #pragma unroll
    for (int c = 0; c < 4; c++) bf[c] = *(const short8*)&Bs[wn + c*16 + frow][kg];
    #pragma unroll
    for (int r = 0; r < 4; r++)
      #pragma unroll
      for (int c = 0; c < 4; c++)
        acc[r][c] = __builtin_amdgcn_mfma_f32_16x16x32_bf16(af[r], bf[c], acc[r][c], 0, 0, 0);
    __syncthreads();
  }
  int crow = (lane >> 4) * 4, ccol = lane & 15;
  #pragma unroll
  for (int r = 0; r < 4; r++)
    #pragma unroll
    for (int c = 0; c < 4; c++)
      #pragma unroll
      for (int i = 0; i < 4; i++){
        int m = m0 + wm + r*16 + crow + i;
        int n = n0 + wn + c*16 + ccol;
        float v = acc[r][c][i] + bias[n];
        if (mode == 0){
          out[(size_t)m*N + n] = v;
        } else {
          int b = m & 31, t = m >> 5;
          v = (v == 0.f) ? -NEGC : v;
          out[((size_t)(b*Tz + t))*Vext + n] = v;
        }
      }
}

// ---------------- Phase A step kernel 1: GRU + target partials ---------------
// grid 128 = 4 bgroups (8 b) x 32 kchunks (16 k); 256 thr = 8b x 16k x 2eh
__global__ __launch_bounds__(256) void step_gru(
    const float* __restrict__ WT1, const float* __restrict__ WT2,
    const float* __restrict__ WqT, const float* __restrict__ giE,
    const float* __restrict__ b_hh,
    const float* __restrict__ ctx_part, const float* __restrict__ denom_part,
    float* __restrict__ hb, float* __restrict__ target_part,
    float* __restrict__ rin, int t){
  __shared__ float ctx_lds[8][Dz];
  __shared__ float h_lds[8][Dz];
  __shared__ float hnew_lds[8][16];
  __shared__ float invd[8];
  int tid = threadIdx.x;
  int bg = blockIdx.x & 3, kc = blockIdx.x >> 2;
  int b8 = tid >> 5, k16 = (tid >> 1) & 15, eh = tid & 1;
  int b = bg*8 + b8, k = kc*16 + k16;
  int par = t & 1;
  const float* h_old = hb + par*Bz*Dz;
  float* h_new = hb + (par^1)*Bz*Dz;
  if (tid < 8){
    float s = 0.f;
    if (t > 0){
      for (int c = 0; c < 4; c++) s += denom_part[(par^1)*128 + c*32 + bg*8 + tid];
      invd[tid] = 1.f/s;
    } else invd[tid] = 0.f;
  }
  __syncthreads();
  for (int i = tid; i < 8*Dz; i += 256){
    int bb = i >> 9, e = i & 511;
    float cv = 0.f;
    if (t > 0){
      for (int c = 0; c < 4; c++) cv += ctx_part[((size_t)c*32 + bg*8 + bb)*Dz + e];
      cv *= invd[bb];
    }
    ctx_lds[bb][e] = cv;
    h_lds[bb][e] = h_old[(size_t)(bg*8+bb)*Dz + e];
    if (t > 0 && kc == 0)
      rin[((size_t)(t-1)*Bz + bg*8 + bb)*G3 + 1024 + e] = cv;
  }
  __syncthreads();
  // 6 partial dots over this thread's e-half
  int e0 = eh * 256;
  float a_ri=0,a_zi=0,a_ni=0,a_rh=0,a_zh=0,a_nh=0;
  const float* w1 = WT1 + k;
  const float* w2 = WT2 + k;
  for (int e = e0; e < e0+256; e++){
    float xc = ctx_lds[b8][e];
    float xh = h_lds[b8][e];
    const float* r1 = w1 + (size_t)e*G3;
    const float* r2 = w2 + (size_t)e*G3;
    a_ri += r1[0]    * xc;
    a_zi += r1[512]  * xc;
    a_ni += r1[1024] * xc;
    a_rh += r2[0]    * xh;
    a_zh += r2[512]  * xh;
    a_nh += r2[1024] * xh;
  }
  a_ri += __shfl_xor(a_ri, 1);
  a_zi += __shfl_xor(a_zi, 1);
  a_ni += __shfl_xor(a_ni, 1);
  a_rh += __shfl_xor(a_rh, 1);
  a_zh += __shfl_xor(a_zh, 1);
  a_nh += __shfl_xor(a_nh, 1);
  if (eh == 0){
    const float* ge = giE + ((size_t)t*Bz + b)*G3;
    float gir = ge[k]        + a_ri;
    float giz = ge[512 + k]  + a_zi;
    float gin = ge[1024 + k] + a_ni;
    float ghr = b_hh[k]        + a_rh;
    float ghz = b_hh[512 + k]  + a_zh;
    float ghn = b_hh[1024 + k] + a_nh;
    float r = sigm(gir + ghr);
    float z = sigm(giz + ghz);
    float nn = tanhfast(gin + r*ghn);
    float hv = (1.f - z)*nn + z*h_lds[b8][k];
    h_new[(size_t)b*Dz + k] = hv;
    rin[((size_t)t*Bz + b)*G3 + 512 + k] = hv;
    hnew_lds[b8][k16] = hv;
  }
  __syncthreads();
  // target partials: target_part[kc][b][j] = sum_k16 hnew * WqT[k][j]
  int j = tid * 2;
  for (int bb = 0; bb < 8; bb++){
    float s0 = 0.f, s1 = 0.f;
    #pragma unroll
    for (int kk = 0; kk < 16; kk++){
      float h = hnew_lds[bb][kk];
      const float* wr = WqT + (size_t)(kc*16 + kk)*Dz + j;
      s0 += h*wr[0]; s1 += h*wr[1];
    }
    float* tp = target_part + ((size_t)kc*32 + bg*8 + bb)*Dz + j;
    tp[0] = s0; tp[1] = s1;
  }
}

// ---------------- Phase A step kernel 2: attention --------------------------
// grid 128 = 32 b x 4 schunks (100 s); 256 thr (4 waves x 25 s)
__global__ __launch_bounds__(256) void step_attn(
    const float* __restrict__ pre, const float* __restrict__ target_part,
    const float* __restrict__ v_att, const float* __restrict__ w_cov,
    const float* __restrict__ memories, const unsigned char* __restrict__ mask,
    float* __restrict__ cov, float* __restrict__ p_buf, float* __restrict__ denom_part,
    float* __restrict__ ctx_part, float* __restrict__ energyAll,
    float* __restrict__ attn_out, float* __restrict__ covh_out, int t){
  __shared__ float tgt[Dz], vl[Dz], wc[Dz];
  __shared__ float cov_l[100], p_l[100];
  __shared__ unsigned char mask_l[100];
  __shared__ float wsum[4];
  int tid = threadIdx.x;
  int b = blockIdx.x >> 2, sc = blockIdx.x & 3;
  int sbase = sc * 100;
  int par = t & 1;
  for (int jj = tid; jj < Dz; jj += 256){
    float s = 0.f;
    for (int kc = 0; kc < 32; kc++) s += target_part[((size_t)kc*32 + b)*Dz + jj];
    tgt[jj] = s;
    vl[jj] = v_att[jj];
    wc[jj] = w_cov[jj];
  }
  float invd = 0.f;
  if (t > 0){
    float s = 0.f;
    for (int c = 0; c < 4; c++) s += denom_part[(par^1)*128 + c*32 + b];
    invd = 1.f/s;
  }
  for (int s = tid; s < 100; s += 256){
    int sg = sbase + s;
    float cv = cov[b*Sz + sg];
    if (t > 0){
      float sp = p_buf[(par^1)*Bz*Sz + b*Sz + sg] * invd;
      attn_out[((size_t)(t-1)*Bz + b)*Sz + sg] = sp;
      cv += sp;
      cov[b*Sz + sg] = cv;
    }
    covh_out[((size_t)t*Bz + b)*Sz + sg] = cv;
    cov_l[s] = cv;
    mask_l[s] = mask[b*Sz + sg];
  }
  __syncthreads();
  int wid = tid >> 6, lane = tid & 63;
  float dsum = 0.f;
  for (int si = 0; si < 25; si++){
    int s = wid*25 + si;
    int sg = sbase + s;
    const float* pr = pre + ((size_t)b*Sz + sg)*Dz;
    float cs = cov_l[s];
    float acc = 0.f;
    #pragma unroll
    for (int i = 0; i < 8; i++){
      int e = lane + 64*i;
      float x = pr[e] + tgt[e] + cs*wc[e];
      acc += vl[e] * tanhfast(x);
    }
    #pragma unroll
    for (int m = 1; m < 64; m <<= 1) acc += __shfl_xor(acc, m);
    float en = mask_l[s] ? -NEGC : acc;
    float p = __expf(en);
    if (lane == 0){
      energyAll[((size_t)t*Bz + b)*Sz + sg] = en;
      p_buf[par*Bz*Sz + b*Sz + sg] = p;
      p_l[s] = p;
      dsum += p;
    }
  }
  if (lane == 0) wsum[wid] = dsum;
  __syncthreads();
  if (tid == 0) denom_part[par*128 + sc*32 + b] = wsum[0]+wsum[1]+wsum[2]+wsum[3];
  for (int e = tid; e < Dz; e += 256){
    float a = 0.f;
    for (int s = 0; s < 100; s++)
      a += p_l[s] * memories[((size_t)b*Sz + sbase + s)*Dz + e];
    ctx_part[((size_t)sc*32 + b)*Dz + e] = a;
  }
}

// ---------------- drain: final ctx (t=63) into rin, final attn row ----------
__global__ __launch_bounds__(256) void drain_k(const float* __restrict__ ctx_part,
    const float* __restrict__ denom_part, const float* __restrict__ p_buf,
    float* __restrict__ rin, float* __restrict__ attn_out){
  int b = blockIdx.x, tid = threadIdx.x;
  float s = 0.f;
  for (int c = 0; c < 4; c++) s += denom_part[1*128 + c*32 + b];
  float invd = 1.f/s;
  for (int e = tid; e < Dz; e += 256){
    float cv = 0.f;
    for (int c = 0; c < 4; c++) cv += ctx_part[((size_t)c*32 + b)*Dz + e];
    rin[((size_t)63*Bz + b)*G3 + 1024 + e] = cv * invd;
  }
  for (int sg = tid; sg < Sz; sg += 256)
    attn_out[((size_t)63*Bz + b)*Sz + sg] = p_buf[1*Bz*Sz + b*Sz + sg] * invd;
}

// ---------------- maxout + cast ---------------------------------------------
__global__ __launch_bounds__(256) void maxout_k(const float* __restrict__ rout,
    unsigned short* __restrict__ mo){
  int m = blockIdx.x, d = threadIdx.x;
  float a = rout[(size_t)m*Dz + 2*d], b = rout[(size_t)m*Dz + 2*d + 1];
  mo[(size_t)m*256 + d] = f2bf(fmaxf(a, b));
}

// ---------------- OOV fill ---------------------------------------------------
__global__ __launch_bounds__(64) void oov_fill(float* __restrict__ out, int Vext){
  int m = blockIdx.x;
  int b = m & 31, t = m >> 5;
  size_t base = (size_t)(b*Tz + t) * Vext;
  for (int v = VOC + threadIdx.x; v < Vext; v += 64)
    out[base + v] = -NEGC;
}

// ---------------- pointer scatter -------------------------------------------
__global__ __launch_bounds__(256) void scatter_k(const int* __restrict__ ext,
    const float* __restrict__ energyAll, float* __restrict__ out, int Vext){
  __shared__ int ex[Sz];
  __shared__ float en[Sz];
  int m = blockIdx.x;
  int t = m >> 5, b = m & 31;
  int tid = threadIdx.x;
  for (int s = tid; s < Sz; s += 256){
    ex[s] = ext[b*Sz + s];
    en[s] = energyAll[(size_t)m*Sz + s];
  }
  __syncthreads();
  size_t base = (size_t)(b*Tz + t) * Vext;
  for (int s = tid; s < Sz; s += 256){
    int v = ex[s];
    float mv = -3.4e38f; int idx = -1;
    for (int s2 = 0; s2 < Sz; s2++){
      if (ex[s2] == v && en[s2] > mv){ mv = en[s2]; idx = s2; }
    }
    if (idx == s && mv != -NEGC){
      if (v < VOC){
        float w = out[base + v] + mv;
        out[base + v] = (w == 0.f) ? -NEGC : w;
      } else {
        out[base + v] = (mv == 0.f) ? -NEGC : mv;
      }
    }
  }
}

// ============================================================================
extern "C" void kernel_launch(void* const* d_in, const int* in_sizes, int n_in,
                              void* d_out, int out_size, void* d_ws, size_t ws_size,
                              hipStream_t stream){
  const float* emb     = (const float*)d_in[0];
  const float* enc0    = (const float*)d_in[1];
  const float* mem     = (const float*)d_in[2];
  const float* W_trans = (const float*)d_in[3];
  const float* b_trans = (const float*)d_in[4];
  const float* W_ih    = (const float*)d_in[5];
  const float* W_hh    = (const float*)d_in[6];
  const float* b_ih    = (const float*)d_in[7];
  const float* b_hh    = (const float*)d_in[8];
  const float* W_pre   = (const float*)d_in[9];
  const float* b_pre   = (const float*)d_in[10];
  const float* W_q     = (const float*)d_in[11];
  const float* W_cov   = (const float*)d_in[12];
  const float* v_att   = (const float*)d_in[13];
  const float* W_ro    = (const float*)d_in[14];
  const float* b_ro    = (const float*)d_in[15];
  const float* W_logit = (const float*)d_in[16];
  const float* b_logit = (const float*)d_in[17];
  const int*   ext     = (const int*)d_in[18];
  const unsigned char* maskp = (const unsigned char*)d_in[19];
  float* out = (float*)d_out;

  const int Vext = (out_size - 2*Tz*Bz*Sz) / (Bz*Tz);

  char* ws = (char*)d_ws;
  size_t off = 0;
  auto alloc = [&](size_t bytes)->void*{
    void* p = ws + off;
    off += (bytes + 255) & ~(size_t)255;
    return p;
  };
  float* embT        = (float*)alloc((size_t)Tz*Bz*Dz*4);
  float* giE         = (float*)alloc((size_t)Tz*Bz*G3*4);
  float* preb        = (float*)alloc((size_t)Bz*Sz*Dz*4);
  float* WT1         = (float*)alloc((size_t)Dz*G3*4);
  float* WT2         = (float*)alloc((size_t)Dz*G3*4);
  float* WqT         = (float*)alloc((size_t)Dz*Dz*4);
  float* hb          = (float*)alloc((size_t)2*Bz*Dz*4);
  float* target_part = (float*)alloc((size_t)32*Bz*Dz*4);
  float* ctx_part    = (float*)alloc((size_t)4*Bz*Dz*4);
  float* denom_part  = (float*)alloc((size_t)2*128*4);
  float* p_buf       = (float*)alloc((size_t)2*Bz*Sz*4);
  float* cov         = (float*)alloc((size_t)Bz*Sz*4);
  float* energyAll   = (float*)alloc((size_t)Tz*Bz*Sz*4);
  float* rin         = (float*)alloc((size_t)Tz*Bz*G3*4);
  float* rout        = (float*)alloc((size_t)Tz*Bz*Dz*4);
  unsigned short* rin_bf = (unsigned short*)alloc((size_t)Tz*Bz*G3*2);
  unsigned short* Wro_bf = (unsigned short*)alloc((size_t)Dz*G3*2);
  unsigned short* mo_bf  = (unsigned short*)alloc((size_t)Tz*Bz*256*2);
  unsigned short* Wl_bf  = (unsigned short*)alloc((size_t)VOC*256*2);

  float* attn_out = out + (size_t)Bz*Tz*Vext;
  float* covh_out = attn_out + (size_t)Tz*Bz*Sz;

  // -------- phase 0: precompute --------
  repack_emb<<<Tz*Bz, 128, 0, stream>>>(emb, embT, rin);
  transpose_k<<<dim3(G3/32, Dz/32), 256, 0, stream>>>(W_ih, 1024, 512, WT1, G3);
  transpose_k<<<dim3(G3/32, Dz/32), 256, 0, stream>>>(W_hh, 512, 0, WT2, G3);
  transpose_k<<<dim3(Dz/32, Dz/32), 256, 0, stream>>>(W_q, 512, 0, WqT, Dz);
  zero_f32<<<(Bz*Sz + 255)/256, 256, 0, stream>>>(cov, Bz*Sz);
  gemm_f32<<<dim3(1, Dz/64), 256, 0, stream>>>(enc0, Dz, W_trans, Dz, b_trans, hb, Dz, Bz, Dz, Dz);
  gemm_f32<<<dim3(Tz*Bz/64, G3/64), 256, 0, stream>>>(embT, Dz, W_ih, 1024, b_ih, giE, G3, Tz*Bz, G3, Dz);
  gemm_f32<<<dim3(Bz*Sz/64, Dz/64), 256, 0, stream>>>(mem, Dz, W_pre, Dz, b_pre, preb, Dz, Bz*Sz, Dz, Dz);
  cast_bf<<<1024, 256, 0, stream>>>(W_ro, Wro_bf, Dz*G3);
  cast_bf<<<2048, 256, 0, stream>>>(W_logit, Wl_bf, VOC*256);

  // -------- phase A: 64 sequential steps, 2 kernels each --------
  for (int t = 0; t < Tz; t++){
    step_gru<<<128, 256, 0, stream>>>(WT1, WT2, WqT, giE, b_hh, ctx_part, denom_part,
                                      hb, target_part, rin, t);
    step_attn<<<128, 256, 0, stream>>>(preb, target_part, v_att, W_cov, mem, maskp,
                                       cov, p_buf, denom_part, ctx_part, energyAll,
                                       attn_out, covh_out, t);
  }
  drain_k<<<Bz, 256, 0, stream>>>(ctx_part, denom_part, p_buf, rin, attn_out);

  // -------- phase B: batched readout -> maxout -> logits -> pointer --------
  cast_bf<<<2048, 256, 0, stream>>>(rin, rin_bf, Tz*Bz*G3);
  mfma_bf16<<<dim3(Tz*Bz/128, Dz/128), 256, 0, stream>>>(rin_bf, G3, Wro_bf, G3, b_ro,
                                                         rout, Dz, G3, 0, 0);
  maxout_k<<<Tz*Bz, 256, 0, stream>>>(rout, mo_bf);
  mfma_bf16<<<dim3(Tz*Bz/128, VOC/128), 256, 0, stream>>>(mo_bf, 256, Wl_bf, 256, b_logit,
                                                          out, VOC, 256, 1, Vext);
  oov_fill<<<Tz*Bz, 64, 0, stream>>>(out, Vext);
  scatter_k<<<Tz*Bz, 256, 0, stream>>>(ext, energyAll, out, Vext);
  (void)in_sizes; (void)n_in; (void)ws_size;
}